// Round 13
// baseline (1671.199 us; speedup 1.0000x reference)
//
#include <hip/hip_runtime.h>

typedef __attribute__((ext_vector_type(8))) short bf16x8;
typedef __attribute__((ext_vector_type(4))) float f32x4;
typedef __attribute__((ext_vector_type(4))) int i32x4;
typedef __attribute__((ext_vector_type(2))) unsigned int u32x2;
typedef unsigned short ushort_t;
typedef unsigned int uint_t;

#define VOCAB 5000
#define HID   512
#define B_    64
#define SEQ_  256
#define H3    1536
#define NPAD  5120
#define NREC  32
#define NGEM  224
#define NTILE (SEQ_ * 40)

__device__ __forceinline__ ushort_t f2bf(float f){
  uint_t u = __float_as_uint(f);
  u = u + 0x7fffu + ((u >> 16) & 1u);
  return (ushort_t)(u >> 16);
}
__device__ __forceinline__ float bf2f(ushort_t s){
  return __uint_as_float(((uint_t)s) << 16);
}

// ---- agent-scope (sc1) helpers: the PROVEN cross-XCD visible flavor ----
__device__ __forceinline__ uint_t agent_load_u32(const uint_t* p){
  uint_t v;
  asm volatile("global_load_dword %0, %1, off sc1\n\t"
               "s_waitcnt vmcnt(0)" : "=v"(v) : "v"(p) : "memory");
  return v;
}
__device__ __forceinline__ void agent_store_u32(uint_t* p, uint_t v){
  asm volatile("global_store_dword %0, %1, off sc1" :: "v"(p), "v"(v) : "memory");
}
__device__ __forceinline__ void agent_store_u64(ushort_t* p, u32x2 v){
  asm volatile("global_store_dwordx2 %0, %1, off sc1" :: "v"(p), "v"(v) : "memory");
}

// ---------------- P1: transpose W_ih (1536 x 5000) -> W_ihT (5000 x 1536) ----------
__global__ void k_transpose(const float* __restrict__ W, float* __restrict__ WT){
  __shared__ float tile[32][33];
  const int bv = blockIdx.x * 32;   // vocab
  const int bg = blockIdx.y * 32;   // 3H
  const int tx = threadIdx.x, ty = threadIdx.y; // 32x8
  #pragma unroll
  for(int r = 0; r < 32; r += 8){
    int g = bg + ty + r, v = bv + tx;
    tile[ty + r][tx] = (v < VOCAB) ? W[(size_t)g * VOCAB + v] : 0.f;
  }
  __syncthreads();
  #pragma unroll
  for(int r = 0; r < 32; r += 8){
    int v = bv + ty + r, g = bg + tx;
    if(v < VOCAB) WT[(size_t)v * H3 + g] = tile[tx][ty + r];
  }
}

// ---------------- P1b: W_out (5000x512) -> bf16 padded (5120x512) ------------------
__global__ void k_cvt_wout(const float* __restrict__ W, ushort_t* __restrict__ WP){
  int idx = (blockIdx.x * 256 + threadIdx.x) * 4;
  if(idx >= NPAD * HID) return;
  float x0 = 0.f, x1 = 0.f, x2 = 0.f, x3 = 0.f;
  if(idx < VOCAB * HID){
    const float4 v = *(const float4*)(W + idx);
    x0 = v.x; x1 = v.y; x2 = v.z; x3 = v.w;
  }
  ushort4 o; o.x = f2bf(x0); o.y = f2bf(x1); o.z = f2bf(x2); o.w = f2bf(x3);
  *(ushort4*)(WP + idx) = o;
}

// ---------------- P2: gather x_proj[s,b,:] = W_ihT[X[b,s]] + b_ih  (bf16 out) ------
__global__ void k_gather(const int* __restrict__ X, const float* __restrict__ WT,
                         const float* __restrict__ bih, ushort_t* __restrict__ xp){
  const int sb = blockIdx.x;            // s*64 + b
  const int s = sb >> 6, b = sb & 63;
  const int x = X[b * SEQ_ + s];
  const float4* src = (const float4*)(WT + (size_t)x * H3);
  const float4* bi  = (const float4*)bih;
  for(int i = threadIdx.x; i < H3 / 4; i += 256){
    float4 v = src[i], c = bi[i];
    ushort4 o;
    o.x = f2bf(v.x + c.x); o.y = f2bf(v.y + c.y);
    o.z = f2bf(v.z + c.z); o.w = f2bf(v.w + c.w);
    ((ushort4*)(xp + (size_t)sb * H3))[i] = o;
  }
}

// ---------------- mega: 32 rec blocks + 224 gem consumers --------------------------
// R12 protocol with three critical-path cuts:
//  - flags PACKED: flags[g] contiguous (one 64B line per domain) -> 1-transaction polls
//  - Y[t] deferred: issued at TOP of step t+1 (ack retires under poll+compute);
//    gem gates tile t on flag >= t+3; post-loop bump covers t=255
//  - no s_sleep in rec poll (tight spin, cheap with packed line)
__global__ void __launch_bounds__(256, 1) k_mega(
    const float* __restrict__ Whh, const float* __restrict__ bhh,
    const float* __restrict__ state, const ushort_t* __restrict__ xp,
    const ushort_t* __restrict__ WP, const float* __restrict__ bout,
    ushort_t* __restrict__ hbuf, ushort_t* __restrict__ Y,
    float* __restrict__ out, float* __restrict__ hT, uint_t* flags)
{
  __shared__ __align__(16) char smem[102912];
  const int bid = blockIdx.x, tid = threadIdx.x;
  const int lane = tid & 63, wv = tid >> 6;
  const int l15 = lane & 15, lhi = lane >> 4;

  if(bid < NREC){
    // ================= recurrence role =================
    ushort_t (*Wl)[520] = (ushort_t(*)[520])smem;
    float* bl = (float*)(smem + 96 * 520 * 2);                 // 99840
    ushort_t (*tsc)[16][20] = (ushort_t(*)[16][20])(smem + 100224);
    const int g = bid;
    const int dom = g >> 4, sub = g & 15;
    const int jb = sub * 32;

    for(int idx = tid; idx < 96 * 512; idx += 256){
      int r = idx >> 9, c = idx & 511;
      int jgr = r / 48, rem = r % 48;
      int gate = rem >> 4, jl = jgr * 16 + (rem & 15);
      Wl[r][c] = f2bf(Whh[((size_t)(gate * HID + jb + jl)) * HID + c]);
    }
    if(tid < 96){
      int jgr = tid / 48, rem = tid % 48;
      int gate = rem >> 4, jl = jgr * 16 + (rem & 15);
      bl[tid] = bhh[gate * HID + jb + jl];
    }

    const int jg = wv >> 1;
    const int jt0 = jb + jg * 16;
    const int j  = jt0 + l15;
    const int rbase = jg * 48;
    const int bband = dom * 32 + (wv & 1) * 16;

    float hprev[4]; int brow[4];
    #pragma unroll
    for(int i = 0; i < 4; i++){
      brow[i] = bband + lhi * 4 + i;
      hprev[i] = state[brow[i] * HID + j];
    }

    // init publication (transposed, one 8B store); barrier also covers Wl staging
    #pragma unroll
    for(int i = 0; i < 4; i++) tsc[wv][lhi * 4 + i][l15] = f2bf(hprev[i]);
    asm volatile("s_waitcnt lgkmcnt(0)" ::: "memory");
    {
      u32x2 rv = *(const u32x2*)&tsc[wv][l15][lhi * 4];
      agent_store_u64(hbuf + (size_t)(bband + l15) * HID + jt0 + lhi * 4, rv);
    }
    asm volatile("s_waitcnt vmcnt(0)" ::: "memory");
    __syncthreads();
    if(tid == 0) agent_store_u32(flags + g, 1u);

    const int fidx = dom * 16 + ((lane + sub) & 15);
    const size_t roff = (size_t)(bband + l15) * HID + jt0 + lhi * 4;
    u32x2 yrv = {0u, 0u};   // previous step's publication, deferred Y write

    for(int t = 0; t < SEQ_; ++t){
      const ushort_t* hin  = hbuf + (t & 1) * (B_ * HID);
      ushort_t*       hout = hbuf + ((t + 1) & 1) * (B_ * HID);

      // deferred Y[t-1]: issue now; ack retires under the poll + compute below,
      // and is provably drained by this step's end-of-step vmcnt(0) (before flag t+2)
      if(t > 0) agent_store_u64(Y + (size_t)(t - 1) * B_ * HID + roff, yrv);

      // gi prefetch (bf16 xp, cached)
      float gir[4], giz[4], gin_[4];
      const ushort_t* xr = xp + (size_t)t * B_ * H3;
      #pragma unroll
      for(int i = 0; i < 4; i++){
        const ushort_t* p = xr + (size_t)brow[i] * H3 + j;
        gir[i] = bf2f(p[0]); giz[i] = bf2f(p[HID]); gin_[i] = bf2f(p[2 * HID]);
      }

      // every wave polls the 16 domain flags (one packed 64B line -> 1 transaction)
      if(lane < 16){
        const uint_t need = (uint_t)(t + 1);
        int gd = 0;
        while(agent_load_u32(flags + fidx) < need){
          if(++gd > 400000) break;   // fail loud instead of hanging
        }
      }

      // read h^t from the coherence point
      i32x4 tmp[16];
      const char* abase = (const char*)(hin + (size_t)(bband + l15) * HID + 8 * lhi);
      #define LDH(i, off) asm volatile("global_load_dwordx4 %0, %1, off offset:" #off " sc1" \
                                       : "=v"(tmp[i]) : "v"(abase) : "memory");
      LDH(0,0)   LDH(1,64)   LDH(2,128)  LDH(3,192)
      LDH(4,256) LDH(5,320)  LDH(6,384)  LDH(7,448)
      LDH(8,512) LDH(9,576)  LDH(10,640) LDH(11,704)
      LDH(12,768) LDH(13,832) LDH(14,896) LDH(15,960)
      #undef LDH
      asm volatile("s_waitcnt vmcnt(0)" ::: "memory");
      __builtin_amdgcn_sched_barrier(0);

      f32x4 acc0 = {0.f,0.f,0.f,0.f}, acc1 = {0.f,0.f,0.f,0.f}, acc2 = {0.f,0.f,0.f,0.f};
      #pragma unroll
      for(int kk = 0; kk < 16; kk++){
        bf16x8 a = __builtin_bit_cast(bf16x8, tmp[kk]);
        const int kc = kk * 32 + 8 * lhi;
        bf16x8 b0 = *(const bf16x8*)&Wl[rbase + l15][kc];
        bf16x8 b1 = *(const bf16x8*)&Wl[rbase + 16 + l15][kc];
        bf16x8 b2 = *(const bf16x8*)&Wl[rbase + 32 + l15][kc];
        acc0 = __builtin_amdgcn_mfma_f32_16x16x32_bf16(a, b0, acc0, 0, 0, 0);
        acc1 = __builtin_amdgcn_mfma_f32_16x16x32_bf16(a, b1, acc1, 0, 0, 0);
        acc2 = __builtin_amdgcn_mfma_f32_16x16x32_bf16(a, b2, acc2, 0, 0, 0);
      }

      const float cr = bl[rbase + l15], cz = bl[rbase + 16 + l15], cn = bl[rbase + 32 + l15];
      float hn4[4];
      #pragma unroll
      for(int i = 0; i < 4; i++){
        float r = 1.f / (1.f + expf(-(gir[i] + acc0[i] + cr)));
        float z = 1.f / (1.f + expf(-(giz[i] + acc1[i] + cz)));
        float n = tanhf(gin_[i] + r * (acc2[i] + cn));
        hn4[i] = (1.f - z) * n + z * hprev[i];
        hprev[i] = hn4[i];
      }

      // intra-wave transpose -> one 8B h store per lane (Y deferred to next step)
      #pragma unroll
      for(int i = 0; i < 4; i++) tsc[wv][lhi * 4 + i][l15] = f2bf(hn4[i]);
      asm volatile("s_waitcnt lgkmcnt(0)" ::: "memory");
      yrv = *(const u32x2*)&tsc[wv][l15][lhi * 4];
      agent_store_u64(hout + roff, yrv);
      asm volatile("s_waitcnt vmcnt(0)" ::: "memory");   // drains h + old Y + gi
      __syncthreads();                                    // single barrier per step
      if(tid == 0) agent_store_u32(flags + g, (uint_t)(t + 2));

      if(t == SEQ_ - 1){
        #pragma unroll
        for(int i = 0; i < 4; i++) hT[brow[i] * HID + j] = hn4[i];
      }
    }

    // final: publish Y[255], drain, bump flag to 258 (= 255+3) for gem
    agent_store_u64(Y + (size_t)(SEQ_ - 1) * B_ * HID + roff, yrv);
    asm volatile("s_waitcnt vmcnt(0)" ::: "memory");
    __syncthreads();
    if(tid == 0) agent_store_u32(flags + g, (uint_t)(SEQ_ + 2));
  } else {
    // ================= out-GEMM role =================
    ushort_t (*At)[520] = (ushort_t(*)[520])smem;
    const int gb = bid - NREC;

    for(int tile = gb; tile < NTILE; tile += NGEM){
      const int t = tile / 40, n0 = (tile % 40) * 128;

      // Y[t] safe when every flag >= t+3 (packed flags: 32 lanes, 2 transactions)
      if(wv == 0){
        const uint_t need = (uint_t)(t + 3);
        int gd = 0;
        while(true){
          uint_t v = 0xffffffffu;
          if(lane < 32) v = agent_load_u32(flags + lane);
          if(__all(v >= need)) break;
          __builtin_amdgcn_s_sleep(64);
          if(++gd > 2000000) break;   // fail loud instead of hanging
        }
      }
      __syncthreads();

      // stage A = Y[t] (64 x 512 bf16) into LDS via sc1 loads (MALL-fresh)
      {
        const int row = tid >> 2, q = tid & 3;
        const char* src = (const char*)(Y + (size_t)t * B_ * HID) + row * 1024 + q * 256;
        i32x4 tv[16];
        #define LDA(i, off) asm volatile("global_load_dwordx4 %0, %1, off offset:" #off " sc1" \
                                         : "=v"(tv[i]) : "v"(src) : "memory");
        LDA(0,0)   LDA(1,16)  LDA(2,32)  LDA(3,48)
        LDA(4,64)  LDA(5,80)  LDA(6,96)  LDA(7,112)
        LDA(8,128) LDA(9,144) LDA(10,160) LDA(11,176)
        LDA(12,192) LDA(13,208) LDA(14,224) LDA(15,240)
        #undef LDA
        asm volatile("s_waitcnt vmcnt(0)" ::: "memory");
        __builtin_amdgcn_sched_barrier(0);
        #pragma unroll
        for(int i = 0; i < 16; i++) *(i32x4*)&At[row][q * 128 + i * 8] = tv[i];
      }
      __syncthreads();

      f32x4 acc[4][2];
      #pragma unroll
      for(int a = 0; a < 4; a++){ acc[a][0] = (f32x4){0,0,0,0}; acc[a][1] = (f32x4){0,0,0,0}; }

      const ushort_t* B0 = WP + (size_t)(n0 + wv * 32 + l15) * HID;
      const ushort_t* B1 = WP + (size_t)(n0 + wv * 32 + 16 + l15) * HID;
      #pragma unroll
      for(int kt = 0; kt < 16; kt++){
        const int kc = kt * 32 + 8 * lhi;
        bf16x8 b0 = *(const bf16x8*)(B0 + kc);
        bf16x8 b1 = *(const bf16x8*)(B1 + kc);
        bf16x8 a0 = *(const bf16x8*)&At[0 * 16 + l15][kc];
        bf16x8 a1 = *(const bf16x8*)&At[1 * 16 + l15][kc];
        bf16x8 a2 = *(const bf16x8*)&At[2 * 16 + l15][kc];
        bf16x8 a3 = *(const bf16x8*)&At[3 * 16 + l15][kc];
        acc[0][0] = __builtin_amdgcn_mfma_f32_16x16x32_bf16(a0, b0, acc[0][0], 0, 0, 0);
        acc[0][1] = __builtin_amdgcn_mfma_f32_16x16x32_bf16(a0, b1, acc[0][1], 0, 0, 0);
        acc[1][0] = __builtin_amdgcn_mfma_f32_16x16x32_bf16(a1, b0, acc[1][0], 0, 0, 0);
        acc[1][1] = __builtin_amdgcn_mfma_f32_16x16x32_bf16(a1, b1, acc[1][1], 0, 0, 0);
        acc[2][0] = __builtin_amdgcn_mfma_f32_16x16x32_bf16(a2, b0, acc[2][0], 0, 0, 0);
        acc[2][1] = __builtin_amdgcn_mfma_f32_16x16x32_bf16(a2, b1, acc[2][1], 0, 0, 0);
        acc[3][0] = __builtin_amdgcn_mfma_f32_16x16x32_bf16(a3, b0, acc[3][0], 0, 0, 0);
        acc[3][1] = __builtin_amdgcn_mfma_f32_16x16x32_bf16(a3, b1, acc[3][1], 0, 0, 0);
      }

      #pragma unroll
      for(int mi = 0; mi < 4; mi++){
        #pragma unroll
        for(int ni = 0; ni < 2; ni++){
          const int v = n0 + wv * 32 + ni * 16 + l15;
          if(v < VOCAB){
            const float bb = bout[v];
            #pragma unroll
            for(int i = 0; i < 4; i++){
              const int sb = t * 64 + mi * 16 + lhi * 4 + i;
              out[(size_t)sb * VOCAB + v] = acc[mi][ni][i] + bb;
            }
          }
        }
      }
      __syncthreads();  // all waves done with At before next tile restages
    }
  }
}

extern "C" void kernel_launch(void* const* d_in, const int* in_sizes, int n_in,
                              void* d_out, int out_size, void* d_ws, size_t ws_size,
                              hipStream_t stream)
{
  const int*   X     = (const int*)  d_in[0];
  const float* state = (const float*)d_in[1];
  const float* Wih   = (const float*)d_in[2];
  const float* Whh   = (const float*)d_in[3];
  const float* bih   = (const float*)d_in[4];
  const float* bhh   = (const float*)d_in[5];
  const float* Wout  = (const float*)d_in[6];
  const float* bout  = (const float*)d_in[7];
  float* out = (float*)d_out;
  float* hT  = out + (size_t)SEQ_ * B_ * VOCAB;

  char* ws = (char*)d_ws;
  const size_t off_WihT  = 4096;
  const size_t off_WoutP = off_WihT  + (size_t)VOCAB * H3  * sizeof(float);
  const size_t off_Y     = off_WoutP + (size_t)NPAD  * HID * sizeof(ushort_t);
  const size_t off_h     = off_Y     + (size_t)SEQ_ * B_ * HID * sizeof(ushort_t);
  const size_t off_xp    = off_h     + (size_t)2 * B_ * HID * sizeof(ushort_t);

  uint_t*   flags = (uint_t*)  ws;                 // 32 packed flags (2 x 64B lines)
  float*    WihT  = (float*)   (ws + off_WihT);
  ushort_t* WoutP = (ushort_t*)(ws + off_WoutP);
  ushort_t* Ybuf  = (ushort_t*)(ws + off_Y);
  ushort_t* hbuf  = (ushort_t*)(ws + off_h);
  ushort_t* xp    = (ushort_t*)(ws + off_xp);

  (void)hipMemsetAsync(d_ws, 0, 4096, stream);
  hipLaunchKernelGGL(k_transpose, dim3(157, 48), dim3(32, 8), 0, stream, Wih, WihT);
  hipLaunchKernelGGL(k_cvt_wout, dim3((NPAD * HID / 4 + 255) / 256), dim3(256), 0, stream, Wout, WoutP);
  hipLaunchKernelGGL(k_gather, dim3(SEQ_ * B_), dim3(256), 0, stream, X, WihT, bih, xp);
  hipLaunchKernelGGL(k_mega, dim3(NREC + NGEM), dim3(256), 0, stream,
                     Whh, bhh, state, xp, WoutP, bout, hbuf, Ybuf, out, hT, flags);
}

// Round 14
// 1208.972 us; speedup vs baseline: 1.3823x; 1.3823x over previous
//
#include <hip/hip_runtime.h>

typedef __attribute__((ext_vector_type(8))) short bf16x8;
typedef __attribute__((ext_vector_type(4))) float f32x4;
typedef __attribute__((ext_vector_type(4))) int i32x4;
typedef __attribute__((ext_vector_type(2))) unsigned int u32x2;
typedef unsigned short ushort_t;
typedef unsigned int uint_t;

#define VOCAB 5000
#define HID   512
#define B_    64
#define SEQ_  256
#define H3    1536
#define NPAD  5120
#define NREC  32
#define NGEM  224
#define NTILE (SEQ_ * 40)

__device__ __forceinline__ ushort_t f2bf(float f){
  uint_t u = __float_as_uint(f);
  u = u + 0x7fffu + ((u >> 16) & 1u);
  return (ushort_t)(u >> 16);
}
__device__ __forceinline__ float bf2f(ushort_t s){
  return __uint_as_float(((uint_t)s) << 16);
}

// ---- agent-scope (sc1) helpers: the PROVEN cross-XCD visible flavor ----
__device__ __forceinline__ uint_t agent_load_u32(const uint_t* p){
  uint_t v;
  asm volatile("global_load_dword %0, %1, off sc1\n\t"
               "s_waitcnt vmcnt(0)" : "=v"(v) : "v"(p) : "memory");
  return v;
}
__device__ __forceinline__ void agent_store_u32(uint_t* p, uint_t v){
  asm volatile("global_store_dword %0, %1, off sc1" :: "v"(p), "v"(v) : "memory");
}
__device__ __forceinline__ void agent_store_u64(ushort_t* p, u32x2 v){
  asm volatile("global_store_dwordx2 %0, %1, off sc1" :: "v"(p), "v"(v) : "memory");
}

// ---------------- P1: transpose W_ih (1536 x 5000) -> W_ihT (5000 x 1536) ----------
__global__ void k_transpose(const float* __restrict__ W, float* __restrict__ WT){
  __shared__ float tile[32][33];
  const int bv = blockIdx.x * 32;   // vocab
  const int bg = blockIdx.y * 32;   // 3H
  const int tx = threadIdx.x, ty = threadIdx.y; // 32x8
  #pragma unroll
  for(int r = 0; r < 32; r += 8){
    int g = bg + ty + r, v = bv + tx;
    tile[ty + r][tx] = (v < VOCAB) ? W[(size_t)g * VOCAB + v] : 0.f;
  }
  __syncthreads();
  #pragma unroll
  for(int r = 0; r < 32; r += 8){
    int v = bv + ty + r, g = bg + tx;
    if(v < VOCAB) WT[(size_t)v * H3 + g] = tile[tx][ty + r];
  }
}

// ---------------- P1b: W_out (5000x512) -> bf16 padded (5120x512) ------------------
__global__ void k_cvt_wout(const float* __restrict__ W, ushort_t* __restrict__ WP){
  int idx = (blockIdx.x * 256 + threadIdx.x) * 4;
  if(idx >= NPAD * HID) return;
  float x0 = 0.f, x1 = 0.f, x2 = 0.f, x3 = 0.f;
  if(idx < VOCAB * HID){
    const float4 v = *(const float4*)(W + idx);
    x0 = v.x; x1 = v.y; x2 = v.z; x3 = v.w;
  }
  ushort4 o; o.x = f2bf(x0); o.y = f2bf(x1); o.z = f2bf(x2); o.w = f2bf(x3);
  *(ushort4*)(WP + idx) = o;
}

// ---------------- P2: gather x_proj[s,b,:] = W_ihT[X[b,s]] + b_ih  (bf16 out) ------
__global__ void k_gather(const int* __restrict__ X, const float* __restrict__ WT,
                         const float* __restrict__ bih, ushort_t* __restrict__ xp){
  const int sb = blockIdx.x;            // s*64 + b
  const int s = sb >> 6, b = sb & 63;
  const int x = X[b * SEQ_ + s];
  const float4* src = (const float4*)(WT + (size_t)x * H3);
  const float4* bi  = (const float4*)bih;
  for(int i = threadIdx.x; i < H3 / 4; i += 256){
    float4 v = src[i], c = bi[i];
    ushort4 o;
    o.x = f2bf(v.x + c.x); o.y = f2bf(v.y + c.y);
    o.z = f2bf(v.z + c.z); o.w = f2bf(v.w + c.w);
    ((ushort4*)(xp + (size_t)sb * H3))[i] = o;
  }
}

// ---------------- mega: 32 rec blocks + 224 gem consumers --------------------------
// R12 protocol (proven 1278us) with ONE change: 4 domains x 8 WGs (16 batches per
// domain, 64 j per WG) -- fan-in 8 instead of 16. W_hh slice lives in REGISTERS
// (48 bf16x8 B-frags per wave, loaded once); biases in 3 scalar regs. LDS W gone.
// Everything else identical: sc1 stores+loads, spread flags (g*32), sleepy poll,
// dwordx2 publication (h + Y both drained before flag), gem gates on flag >= t+2.
__global__ void __launch_bounds__(256, 1) k_mega(
    const float* __restrict__ Whh, const float* __restrict__ bhh,
    const float* __restrict__ state, const ushort_t* __restrict__ xp,
    const ushort_t* __restrict__ WP, const float* __restrict__ bout,
    ushort_t* __restrict__ hbuf, ushort_t* __restrict__ Y,
    float* __restrict__ out, float* __restrict__ hT, uint_t* flags)
{
  __shared__ __align__(16) char smem[102912];   // pins 1 block/CU for both roles
  const int bid = blockIdx.x, tid = threadIdx.x;
  const int lane = tid & 63, wv = tid >> 6;
  const int l15 = lane & 15, lhi = lane >> 4;

  if(bid < NREC){
    // ================= recurrence role =================
    ushort_t (*tsc)[16][20] = (ushort_t(*)[16][20])(smem + 100224);
    const int g = bid;
    const int dom = g >> 3, sub = g & 7;       // 4 domains x 8 WGs
    const int jbwg = sub * 64;                 // WG owns 64 j
    const int jg = wv;                         // wave's 16-j subband
    const int jt0 = jbwg + jg * 16;
    const int j  = jt0 + l15;
    const int bband = dom * 16;                // domain owns 16 batches

    // biases in registers
    const float cr = bhh[j], cz = bhh[HID + j], cn = bhh[2 * HID + j];

    // W_hh B-fragments in registers: wb[gate*16+kk] =
    //   Whh[gate*512 + j][kk*32 + 8*lhi .. +8] as bf16x8  (192 VGPRs)
    bf16x8 wb[48];
    #pragma unroll
    for(int gate = 0; gate < 3; gate++){
      #pragma unroll
      for(int kk = 0; kk < 16; kk++){
        const float* wsrc = Whh + (size_t)(gate * HID + j) * HID + kk * 32 + 8 * lhi;
        float4 w0 = *(const float4*)(wsrc);
        float4 w1 = *(const float4*)(wsrc + 4);
        bf16x8 bf;
        bf[0] = (short)f2bf(w0.x); bf[1] = (short)f2bf(w0.y);
        bf[2] = (short)f2bf(w0.z); bf[3] = (short)f2bf(w0.w);
        bf[4] = (short)f2bf(w1.x); bf[5] = (short)f2bf(w1.y);
        bf[6] = (short)f2bf(w1.z); bf[7] = (short)f2bf(w1.w);
        wb[gate * 16 + kk] = bf;
      }
    }

    float hprev[4]; int brow[4];
    #pragma unroll
    for(int i = 0; i < 4; i++){
      brow[i] = bband + lhi * 4 + i;
      hprev[i] = state[brow[i] * HID + j];
    }

    // init publication (transposed, one 8B store)
    #pragma unroll
    for(int i = 0; i < 4; i++) tsc[wv][lhi * 4 + i][l15] = f2bf(hprev[i]);
    asm volatile("s_waitcnt lgkmcnt(0)" ::: "memory");
    {
      u32x2 rv = *(const u32x2*)&tsc[wv][l15][lhi * 4];
      agent_store_u64(hbuf + (size_t)(bband + l15) * HID + jt0 + lhi * 4, rv);
    }
    asm volatile("s_waitcnt vmcnt(0)" ::: "memory");
    __syncthreads();
    if(tid == 0) agent_store_u32(flags + g * 32, 1u);

    const int fidx = dom * 8 + ((lane + sub) & 7);   // staggered, fan-in 8
    const size_t roff = (size_t)(bband + l15) * HID + jt0 + lhi * 4;

    for(int t = 0; t < SEQ_; ++t){
      const ushort_t* hin  = hbuf + (t & 1) * (B_ * HID);
      ushort_t*       hout = hbuf + ((t + 1) & 1) * (B_ * HID);

      // gi prefetch (bf16 xp, cached); drains in the poll's first vmcnt
      float gir[4], giz[4], gin_[4];
      const ushort_t* xr = xp + (size_t)t * B_ * H3;
      #pragma unroll
      for(int i = 0; i < 4; i++){
        const ushort_t* p = xr + (size_t)brow[i] * H3 + j;
        gir[i] = bf2f(p[0]); giz[i] = bf2f(p[HID]); gin_[i] = bf2f(p[2 * HID]);
      }

      // every wave polls its domain's 8 flags (spread 128B lines)
      if(lane < 8){
        const uint_t need = (uint_t)(t + 1);
        int gd = 0;
        while(agent_load_u32(flags + fidx * 32) < need){
          __builtin_amdgcn_s_sleep(1);
          if(++gd > 200000) break;   // fail loud instead of hanging
        }
      }

      // read h^t (16 domain batches x 512) from the coherence point
      i32x4 tmp[16];
      const char* abase = (const char*)(hin + (size_t)(bband + l15) * HID + 8 * lhi);
      #define LDH(i, off) asm volatile("global_load_dwordx4 %0, %1, off offset:" #off " sc1" \
                                       : "=v"(tmp[i]) : "v"(abase) : "memory");
      LDH(0,0)   LDH(1,64)   LDH(2,128)  LDH(3,192)
      LDH(4,256) LDH(5,320)  LDH(6,384)  LDH(7,448)
      LDH(8,512) LDH(9,576)  LDH(10,640) LDH(11,704)
      LDH(12,768) LDH(13,832) LDH(14,896) LDH(15,960)
      #undef LDH
      asm volatile("s_waitcnt vmcnt(0)" ::: "memory");
      __builtin_amdgcn_sched_barrier(0);

      f32x4 acc0 = {0.f,0.f,0.f,0.f}, acc1 = {0.f,0.f,0.f,0.f}, acc2 = {0.f,0.f,0.f,0.f};
      #pragma unroll
      for(int kk = 0; kk < 16; kk++){
        bf16x8 a = __builtin_bit_cast(bf16x8, tmp[kk]);
        acc0 = __builtin_amdgcn_mfma_f32_16x16x32_bf16(a, wb[kk],      acc0, 0, 0, 0);
        acc1 = __builtin_amdgcn_mfma_f32_16x16x32_bf16(a, wb[16 + kk], acc1, 0, 0, 0);
        acc2 = __builtin_amdgcn_mfma_f32_16x16x32_bf16(a, wb[32 + kk], acc2, 0, 0, 0);
      }

      float hn4[4];
      #pragma unroll
      for(int i = 0; i < 4; i++){
        float r = 1.f / (1.f + expf(-(gir[i] + acc0[i] + cr)));
        float z = 1.f / (1.f + expf(-(giz[i] + acc1[i] + cz)));
        float n = tanhf(gin_[i] + r * (acc2[i] + cn));
        hn4[i] = (1.f - z) * n + z * hprev[i];
        hprev[i] = hn4[i];
      }

      // intra-wave transpose -> one 8B h store + one 8B Y store per lane
      #pragma unroll
      for(int i = 0; i < 4; i++) tsc[wv][lhi * 4 + i][l15] = f2bf(hn4[i]);
      asm volatile("s_waitcnt lgkmcnt(0)" ::: "memory");
      {
        u32x2 rv = *(const u32x2*)&tsc[wv][l15][lhi * 4];
        agent_store_u64(hout + roff, rv);
        agent_store_u64(Y + (size_t)t * B_ * HID + roff, rv);
      }
      asm volatile("s_waitcnt vmcnt(0)" ::: "memory");   // drain h + Y (2 stores)
      __syncthreads();                                    // single barrier per step
      if(tid == 0) agent_store_u32(flags + g * 32, (uint_t)(t + 2));

      if(t == SEQ_ - 1){
        #pragma unroll
        for(int i = 0; i < 4; i++) hT[brow[i] * HID + j] = hn4[i];
      }
    }
  } else {
    // ================= out-GEMM role =================
    ushort_t (*At)[520] = (ushort_t(*)[520])smem;
    const int gb = bid - NREC;

    for(int tile = gb; tile < NTILE; tile += NGEM){
      const int t = tile / 40, n0 = (tile % 40) * 128;

      // wave 0 polls all 32 flags >= t+2 with sleepy backoff
      if(wv == 0){
        const uint_t need = (uint_t)(t + 2);
        int gd = 0;
        while(true){
          uint_t v = 0xffffffffu;
          if(lane < 32) v = agent_load_u32(flags + lane * 32);
          if(__all(v >= need)) break;
          __builtin_amdgcn_s_sleep(64);
          if(++gd > 2000000) break;   // fail loud instead of hanging
        }
      }
      __syncthreads();

      // stage A = Y[t] (64 x 512 bf16) into LDS via sc1 loads (MALL-fresh)
      {
        const int row = tid >> 2, q = tid & 3;
        const char* src = (const char*)(Y + (size_t)t * B_ * HID) + row * 1024 + q * 256;
        i32x4 tv[16];
        #define LDA(i, off) asm volatile("global_load_dwordx4 %0, %1, off offset:" #off " sc1" \
                                         : "=v"(tv[i]) : "v"(src) : "memory");
        LDA(0,0)   LDA(1,16)  LDA(2,32)  LDA(3,48)
        LDA(4,64)  LDA(5,80)  LDA(6,96)  LDA(7,112)
        LDA(8,128) LDA(9,144) LDA(10,160) LDA(11,176)
        LDA(12,192) LDA(13,208) LDA(14,224) LDA(15,240)
        #undef LDA
        asm volatile("s_waitcnt vmcnt(0)" ::: "memory");
        __builtin_amdgcn_sched_barrier(0);
        #pragma unroll
        for(int i = 0; i < 16; i++) *(i32x4*)&At[row][q * 128 + i * 8] = tv[i];
      }
      __syncthreads();

      f32x4 acc[4][2];
      #pragma unroll
      for(int a = 0; a < 4; a++){ acc[a][0] = (f32x4){0,0,0,0}; acc[a][1] = (f32x4){0,0,0,0}; }

      const ushort_t* B0 = WP + (size_t)(n0 + wv * 32 + l15) * HID;
      const ushort_t* B1 = WP + (size_t)(n0 + wv * 32 + 16 + l15) * HID;
      #pragma unroll
      for(int kt = 0; kt < 16; kt++){
        const int kc = kt * 32 + 8 * lhi;
        bf16x8 b0 = *(const bf16x8*)(B0 + kc);
        bf16x8 b1 = *(const bf16x8*)(B1 + kc);
        bf16x8 a0 = *(const bf16x8*)&At[0 * 16 + l15][kc];
        bf16x8 a1 = *(const bf16x8*)&At[1 * 16 + l15][kc];
        bf16x8 a2 = *(const bf16x8*)&At[2 * 16 + l15][kc];
        bf16x8 a3 = *(const bf16x8*)&At[3 * 16 + l15][kc];
        acc[0][0] = __builtin_amdgcn_mfma_f32_16x16x32_bf16(a0, b0, acc[0][0], 0, 0, 0);
        acc[0][1] = __builtin_amdgcn_mfma_f32_16x16x32_bf16(a0, b1, acc[0][1], 0, 0, 0);
        acc[1][0] = __builtin_amdgcn_mfma_f32_16x16x32_bf16(a1, b0, acc[1][0], 0, 0, 0);
        acc[1][1] = __builtin_amdgcn_mfma_f32_16x16x32_bf16(a1, b1, acc[1][1], 0, 0, 0);
        acc[2][0] = __builtin_amdgcn_mfma_f32_16x16x32_bf16(a2, b0, acc[2][0], 0, 0, 0);
        acc[2][1] = __builtin_amdgcn_mfma_f32_16x16x32_bf16(a2, b1, acc[2][1], 0, 0, 0);
        acc[3][0] = __builtin_amdgcn_mfma_f32_16x16x32_bf16(a3, b0, acc[3][0], 0, 0, 0);
        acc[3][1] = __builtin_amdgcn_mfma_f32_16x16x32_bf16(a3, b1, acc[3][1], 0, 0, 0);
      }

      #pragma unroll
      for(int mi = 0; mi < 4; mi++){
        #pragma unroll
        for(int ni = 0; ni < 2; ni++){
          const int v = n0 + wv * 32 + ni * 16 + l15;
          if(v < VOCAB){
            const float bb = bout[v];
            #pragma unroll
            for(int i = 0; i < 4; i++){
              const int sb = t * 64 + mi * 16 + lhi * 4 + i;
              out[(size_t)sb * VOCAB + v] = acc[mi][ni][i] + bb;
            }
          }
        }
      }
      __syncthreads();  // all waves done with At before next tile restages
    }
  }
}

extern "C" void kernel_launch(void* const* d_in, const int* in_sizes, int n_in,
                              void* d_out, int out_size, void* d_ws, size_t ws_size,
                              hipStream_t stream)
{
  const int*   X     = (const int*)  d_in[0];
  const float* state = (const float*)d_in[1];
  const float* Wih   = (const float*)d_in[2];
  const float* Whh   = (const float*)d_in[3];
  const float* bih   = (const float*)d_in[4];
  const float* bhh   = (const float*)d_in[5];
  const float* Wout  = (const float*)d_in[6];
  const float* bout  = (const float*)d_in[7];
  float* out = (float*)d_out;
  float* hT  = out + (size_t)SEQ_ * B_ * VOCAB;

  char* ws = (char*)d_ws;
  const size_t off_WihT  = 4096;
  const size_t off_WoutP = off_WihT  + (size_t)VOCAB * H3  * sizeof(float);
  const size_t off_Y     = off_WoutP + (size_t)NPAD  * HID * sizeof(ushort_t);
  const size_t off_h     = off_Y     + (size_t)SEQ_ * B_ * HID * sizeof(ushort_t);
  const size_t off_xp    = off_h     + (size_t)2 * B_ * HID * sizeof(ushort_t);

  uint_t*   flags = (uint_t*)  ws;                 // 32 flags, 128B apart (4KB)
  float*    WihT  = (float*)   (ws + off_WihT);
  ushort_t* WoutP = (ushort_t*)(ws + off_WoutP);
  ushort_t* Ybuf  = (ushort_t*)(ws + off_Y);
  ushort_t* hbuf  = (ushort_t*)(ws + off_h);
  ushort_t* xp    = (ushort_t*)(ws + off_xp);

  (void)hipMemsetAsync(d_ws, 0, 4096, stream);
  hipLaunchKernelGGL(k_transpose, dim3(157, 48), dim3(32, 8), 0, stream, Wih, WihT);
  hipLaunchKernelGGL(k_cvt_wout, dim3((NPAD * HID / 4 + 255) / 256), dim3(256), 0, stream, Wout, WoutP);
  hipLaunchKernelGGL(k_gather, dim3(SEQ_ * B_), dim3(256), 0, stream, X, WihT, bih, xp);
  hipLaunchKernelGGL(k_mega, dim3(NREC + NGEM), dim3(256), 0, stream,
                     Whh, bhh, state, xp, WoutP, bout, hbuf, Ybuf, out, hT, flags);
}